// Round 1
// baseline (1813.384 us; speedup 1.0000x reference)
//
#include <hip/hip_runtime.h>
#include <math.h>

#define B_Q   128
#define DIM   512
#define NCORP 500000
#define TN    64      // corpus rows per block tile
#define KB    32      // k-chunk staged in LDS

__device__ __forceinline__ void ins3(float s, int id,
                                     float& b0, float& b1, float& b2,
                                     int& i0, int& i1, int& i2) {
    if (s > b0)      { b2 = b1; i2 = i1; b1 = b0; i1 = i0; b0 = s; i0 = id; }
    else if (s > b1) { b2 = b1; i2 = i1; b1 = s;  i1 = id; }
    else if (s > b2) { b2 = s;  i2 = id; }
}

// ---------------------------------------------------------------------------
// Kernel A: query = query_r @ W ; L2-normalize rows ; store transposed
// qnT[d][b]  (d-major so the scan kernel loads k-slices coalesced)
// ---------------------------------------------------------------------------
__global__ void proj_norm_kernel(const float* __restrict__ qr,
                                 const float* __restrict__ W,
                                 float* __restrict__ qnT) {
    __shared__ float qrow[DIM];
    __shared__ float red[256];
    const int b = blockIdx.x;   // query row
    const int t = threadIdx.x;  // 0..255

    qrow[t]       = qr[b * DIM + t];
    qrow[t + 256] = qr[b * DIM + t + 256];
    __syncthreads();

    float acc0 = 0.f, acc1 = 0.f;
#pragma unroll 8
    for (int k = 0; k < DIM; ++k) {
        const float q = qrow[k];
        acc0 = fmaf(q, W[k * DIM + t],       acc0);
        acc1 = fmaf(q, W[k * DIM + t + 256], acc1);
    }

    red[t] = acc0 * acc0 + acc1 * acc1;
    __syncthreads();
    for (int s = 128; s > 0; s >>= 1) {
        if (t < s) red[t] += red[t + s];
        __syncthreads();
    }
    const float inv = 1.0f / fmaxf(sqrtf(red[0]), 1e-6f);

    qnT[t * B_Q + b]         = acc0 * inv;
    qnT[(t + 256) * B_Q + b] = acc1 * inv;
}

// ---------------------------------------------------------------------------
// Kernel B: fused cosine scan + per-block top-3.
// Block tile: 128 queries x 64 corpus rows. Thread tile: 4q x 8c.
// Corpus norms accumulated during LDS staging (single corpus pass).
// ---------------------------------------------------------------------------
__global__ __launch_bounds__(256, 2) void scan_topk_kernel(
        const float* __restrict__ corpus,
        const float* __restrict__ qnT,
        float* __restrict__ cand_s,
        int*   __restrict__ cand_i,
        int nblk) {
    __shared__ __align__(16) float qs[KB][B_Q];   // 16 KB, k-major
    __shared__ __align__(16) float cs[KB][TN];    //  8 KB, k-major (transposed on store)
    __shared__ float normp[TN][8];                //  2 KB norm partials
    __shared__ float msc[B_Q * 8 * 3];            // 12 KB merge scores
    __shared__ int   mid[B_Q * 8 * 3];            // 12 KB merge idx

    const int t  = threadIdx.x;
    const int tq = t & 31;   // query group: queries tq*4 .. tq*4+3
    const int tc = t >> 5;   // corpus group: rows tc*8 .. tc*8+7

    float ts[4][3];
    int   ti[4][3];
#pragma unroll
    for (int q = 0; q < 4; ++q)
#pragma unroll
        for (int j = 0; j < 3; ++j) { ts[q][j] = -1e30f; ti[q][j] = 0; }

    const int rowA = t >> 3;        // 0..31 (staging row ownership)
    const int rowB = rowA + 32;
    const int kq   = (t & 7) << 2;  // float4 col offset in k-chunk
    const int ntiles = (NCORP + TN - 1) / TN;

    for (int tile = blockIdx.x; tile < ntiles; tile += nblk) {
        const int r0 = tile * TN;
        float acc[4][8];
#pragma unroll
        for (int q = 0; q < 4; ++q)
#pragma unroll
            for (int c = 0; c < 8; ++c) acc[q][c] = 0.f;
        float nsqA = 0.f, nsqB = 0.f;

        for (int k0 = 0; k0 < DIM; k0 += KB) {
            // stage qn slice [k0..k0+31][0..127]  (contiguous copy)
            const float4* qsrc = (const float4*)(qnT + (size_t)k0 * B_Q);
            float4* qdst = (float4*)(&qs[0][0]);
#pragma unroll
            for (int p = 0; p < 4; ++p) qdst[t + 256 * p] = qsrc[t + 256 * p];

            // stage corpus tile (transpose to k-major) + norm partials
            {
                const int rA  = r0 + rowA;
                const int rAc = rA < NCORP ? rA : NCORP - 1;
                float4 v = *(const float4*)(corpus + (size_t)rAc * DIM + k0 + kq);
                if (rA >= NCORP) { v.x = v.y = v.z = v.w = 0.f; }
                nsqA = fmaf(v.x, v.x, nsqA); nsqA = fmaf(v.y, v.y, nsqA);
                nsqA = fmaf(v.z, v.z, nsqA); nsqA = fmaf(v.w, v.w, nsqA);
                cs[kq + 0][rowA] = v.x; cs[kq + 1][rowA] = v.y;
                cs[kq + 2][rowA] = v.z; cs[kq + 3][rowA] = v.w;

                const int rB  = r0 + rowB;
                const int rBc = rB < NCORP ? rB : NCORP - 1;
                float4 w = *(const float4*)(corpus + (size_t)rBc * DIM + k0 + kq);
                if (rB >= NCORP) { w.x = w.y = w.z = w.w = 0.f; }
                nsqB = fmaf(w.x, w.x, nsqB); nsqB = fmaf(w.y, w.y, nsqB);
                nsqB = fmaf(w.z, w.z, nsqB); nsqB = fmaf(w.w, w.w, nsqB);
                cs[kq + 0][rowB] = w.x; cs[kq + 1][rowB] = w.y;
                cs[kq + 2][rowB] = w.z; cs[kq + 3][rowB] = w.w;
            }
            __syncthreads();

#pragma unroll
            for (int k = 0; k < KB; ++k) {
                const float4 qv = *(const float4*)(&qs[k][tq << 2]);
                const float4 ca = *(const float4*)(&cs[k][tc << 3]);
                const float4 cb = *(const float4*)(&cs[k][(tc << 3) + 4]);
                const float qa[4] = {qv.x, qv.y, qv.z, qv.w};
                const float cc[8] = {ca.x, ca.y, ca.z, ca.w,
                                     cb.x, cb.y, cb.z, cb.w};
#pragma unroll
                for (int q = 0; q < 4; ++q)
#pragma unroll
                    for (int c = 0; c < 8; ++c)
                        acc[q][c] = fmaf(qa[q], cc[c], acc[q][c]);
            }
            __syncthreads();
        }

        // reduce corpus-row norms
        normp[rowA][t & 7] = nsqA;
        normp[rowB][t & 7] = nsqB;
        __syncthreads();

#pragma unroll
        for (int c = 0; c < 8; ++c) {
            const int row = (tc << 3) + c;
            const int r   = r0 + row;
            float nsq = 0.f;
#pragma unroll
            for (int e = 0; e < 8; ++e) nsq += normp[row][e];
            const float inv = 1.0f / fmaxf(sqrtf(nsq), 1e-6f);
            if (r < NCORP) {
#pragma unroll
                for (int q = 0; q < 4; ++q) {
                    const float s = acc[q][c] * inv;
                    ins3(s, r, ts[q][0], ts[q][1], ts[q][2],
                               ti[q][0], ti[q][1], ti[q][2]);
                }
            }
        }
        __syncthreads();
    }

    // block-level merge: 8 corpus-groups per query -> per-block top-3
#pragma unroll
    for (int q = 0; q < 4; ++q) {
        const int qq = (tq << 2) + q;
#pragma unroll
        for (int j = 0; j < 3; ++j) {
            msc[qq * 24 + tc * 3 + j] = ts[q][j];
            mid[qq * 24 + tc * 3 + j] = ti[q][j];
        }
    }
    __syncthreads();
    if (t < B_Q) {
        float b0 = -1e30f, b1 = -1e30f, b2 = -1e30f;
        int   i0 = 0, i1 = 0, i2 = 0;
        for (int e = 0; e < 24; ++e)
            ins3(msc[t * 24 + e], mid[t * 24 + e], b0, b1, b2, i0, i1, i2);
        const size_t base = ((size_t)blockIdx.x * B_Q + t) * 3;
        cand_s[base + 0] = b0; cand_s[base + 1] = b1; cand_s[base + 2] = b2;
        cand_i[base + 0] = i0; cand_i[base + 1] = i1; cand_i[base + 2] = i2;
    }
}

// ---------------------------------------------------------------------------
// Kernel C: reduce per-block candidates -> global top-3 per query; write out.
// d_out: [0..383] scores f32, [384..767] indices stored as f32 values.
// ---------------------------------------------------------------------------
__global__ void final_topk_kernel(const float* __restrict__ cand_s,
                                  const int*   __restrict__ cand_i,
                                  int nblk,
                                  float* __restrict__ out) {
    __shared__ float ls[256 * 3];
    __shared__ int   li[256 * 3];
    const int q = blockIdx.x;
    const int t = threadIdx.x;

    float b0 = -1e30f, b1 = -1e30f, b2 = -1e30f;
    int   i0 = 0, i1 = 0, i2 = 0;
    for (int blk = t; blk < nblk; blk += 256) {
        const size_t base = ((size_t)blk * B_Q + q) * 3;
#pragma unroll
        for (int j = 0; j < 3; ++j)
            ins3(cand_s[base + j], cand_i[base + j], b0, b1, b2, i0, i1, i2);
    }
    ls[t * 3 + 0] = b0; ls[t * 3 + 1] = b1; ls[t * 3 + 2] = b2;
    li[t * 3 + 0] = i0; li[t * 3 + 1] = i1; li[t * 3 + 2] = i2;
    __syncthreads();

    if (t == 0) {
        float c0 = -1e30f, c1 = -1e30f, c2 = -1e30f;
        int   j0 = 0, j1 = 0, j2 = 0;
        for (int e = 0; e < 256 * 3; ++e)
            ins3(ls[e], li[e], c0, c1, c2, j0, j1, j2);
        out[q * 3 + 0] = c0;
        out[q * 3 + 1] = c1;
        out[q * 3 + 2] = c2;
        out[B_Q * 3 + q * 3 + 0] = (float)j0;
        out[B_Q * 3 + q * 3 + 1] = (float)j1;
        out[B_Q * 3 + q * 3 + 2] = (float)j2;
    }
}

// ---------------------------------------------------------------------------
extern "C" void kernel_launch(void* const* d_in, const int* in_sizes, int n_in,
                              void* d_out, int out_size, void* d_ws, size_t ws_size,
                              hipStream_t stream) {
    const float* qr     = (const float*)d_in[0];  // [128,512]
    const float* corpus = (const float*)d_in[1];  // [500000,512]
    const float* W      = (const float*)d_in[2];  // [512,512]
    // d_in[3] = k (==3), fixed by output shape

    float* out = (float*)d_out;
    char*  ws  = (char*)d_ws;

    float* qnT = (float*)ws;                              // 512*128 f32 = 256 KB
    const size_t qn_bytes = (size_t)DIM * B_Q * sizeof(float);

    const size_t per_blk = (size_t)B_Q * 3 * (sizeof(float) + sizeof(int));
    int nblk = 1024;
    const size_t avail = ws_size > qn_bytes ? ws_size - qn_bytes : 0;
    if ((size_t)nblk * per_blk > avail) nblk = (int)(avail / per_blk);
    const int ntiles = (NCORP + TN - 1) / TN;
    if (nblk > ntiles) nblk = ntiles;
    if (nblk < 1) nblk = 1;

    float* cand_s = (float*)(ws + qn_bytes);
    int*   cand_i = (int*)(ws + qn_bytes + (size_t)nblk * B_Q * 3 * sizeof(float));

    proj_norm_kernel<<<B_Q, 256, 0, stream>>>(qr, W, qnT);
    scan_topk_kernel<<<nblk, 256, 0, stream>>>(corpus, qnT, cand_s, cand_i, nblk);
    final_topk_kernel<<<B_Q, 256, 0, stream>>>(cand_s, cand_i, nblk, out);
}

// Round 2
// 1145.579 us; speedup vs baseline: 1.5829x; 1.5829x over previous
//
#include <hip/hip_runtime.h>
#include <math.h>

#define B_Q   128
#define DIM   512
#define NCORP 500000
#define TR    128           // corpus rows per block tile
#define NCH   16            // K chunks of 32 (512/32)

typedef short short8 __attribute__((ext_vector_type(8)));
typedef float floatx4 __attribute__((ext_vector_type(4)));

__device__ __forceinline__ void ins3(float s, int id,
                                     float& b0, float& b1, float& b2,
                                     int& i0, int& i1, int& i2) {
    if (s > b0)      { b2 = b1; i2 = i1; b1 = b0; i1 = i0; b0 = s; i0 = id; }
    else if (s > b1) { b2 = b1; i2 = i1; b1 = s;  i1 = id; }
    else if (s > b2) { b2 = s;  i2 = id; }
}

// f32 -> (hi, lo) bf16, both RNE.  x ~= hi + lo with residual <= 2^-17 |x|.
__device__ __forceinline__ void split_bf16(float x, unsigned short& h, unsigned short& l) {
    unsigned u = __float_as_uint(x);
    unsigned hr = (u + 0x7FFFu + ((u >> 16) & 1u)) >> 16;
    h = (unsigned short)hr;
    float hf = __uint_as_float(hr << 16);
    float lf = x - hf;
    unsigned v = __float_as_uint(lf);
    l = (unsigned short)((v + 0x7FFFu + ((v >> 16) & 1u)) >> 16);
}

// ---------------------------------------------------------------------------
// Kernel A: query = query_r @ W ; L2-normalize ; split hi/lo bf16 ; write in
// MFMA B-fragment-linear layout:
//   qws ushort idx = kc*8192 + qg*512 + (g*16 + q15)*8 + e   (hi; lo at +4096)
// where kc=d>>5, g=(d&31)>>3, e=d&7, qg=b>>4, q15=b&15.
// ---------------------------------------------------------------------------
__global__ void proj_split_kernel(const float* __restrict__ qr,
                                  const float* __restrict__ W,
                                  unsigned short* __restrict__ qws) {
    __shared__ float qrow[DIM];
    __shared__ float red[256];
    const int b = blockIdx.x;   // query row
    const int t = threadIdx.x;  // 0..255

    qrow[t]       = qr[b * DIM + t];
    qrow[t + 256] = qr[b * DIM + t + 256];
    __syncthreads();

    float acc0 = 0.f, acc1 = 0.f;
#pragma unroll 8
    for (int k = 0; k < DIM; ++k) {
        const float q = qrow[k];
        acc0 = fmaf(q, W[k * DIM + t],       acc0);
        acc1 = fmaf(q, W[k * DIM + t + 256], acc1);
    }

    red[t] = acc0 * acc0 + acc1 * acc1;
    __syncthreads();
    for (int s = 128; s > 0; s >>= 1) {
        if (t < s) red[t] += red[t + s];
        __syncthreads();
    }
    const float inv = 1.0f / fmaxf(sqrtf(red[0]), 1e-6f);

    const int qg = b >> 4, q15 = b & 15;
#pragma unroll
    for (int half = 0; half < 2; ++half) {
        const int d = t + half * 256;
        const float x = (half == 0 ? acc0 : acc1) * inv;
        unsigned short h, lo_;
        split_bf16(x, h, lo_);
        const int kc = d >> 5, kk = d & 31, g = kk >> 3, e = kk & 7;
        const size_t idx = (size_t)kc * 8192 + qg * 512 + (g * 16 + q15) * 8 + e;
        qws[idx]        = h;
        qws[idx + 4096] = lo_;
    }
}

// ---------------------------------------------------------------------------
// Kernel B: MFMA cosine scan + fused top-3.
// Block: 256 thr / 4 waves. Tile: 128 corpus rows x 128 queries, K chunks of 32.
// 3-pass hi/lo split accumulated into one f32 acc: qh*ch + qh*cl + ql*ch.
// ---------------------------------------------------------------------------
struct StageRegs { float4 c[4]; uint4 q[4]; };

__device__ __forceinline__ void stage_load(StageRegs& r,
                                           const float* __restrict__ corpus,
                                           const unsigned short* __restrict__ qws,
                                           int r0, int kc, int t) {
    const int srow = t >> 1, shalf = t & 1;
    int rr = r0 + srow; if (rr > NCORP - 1) rr = NCORP - 1;
    const float* src = corpus + (size_t)rr * DIM + kc * 32 + shalf * 16;
#pragma unroll
    for (int i = 0; i < 4; ++i) r.c[i] = *(const float4*)(src + i * 4);
    const uint4* qsrc = (const uint4*)(qws + (size_t)kc * 8192);
#pragma unroll
    for (int i = 0; i < 4; ++i) r.q[i] = qsrc[t + 256 * i];
}

__device__ __forceinline__ float stage_write(const StageRegs& r,
                                             unsigned short* Ahi, unsigned short* Alo,
                                             unsigned short* Q, int t) {
    const int srow = t >> 1, shalf = t & 1;
    float v[16];
#pragma unroll
    for (int i = 0; i < 4; ++i) {
        v[i * 4 + 0] = r.c[i].x; v[i * 4 + 1] = r.c[i].y;
        v[i * 4 + 2] = r.c[i].z; v[i * 4 + 3] = r.c[i].w;
    }
    float nsq = 0.f;
    unsigned short hi[16], lo[16];
#pragma unroll
    for (int j = 0; j < 16; ++j) {
        nsq = fmaf(v[j], v[j], nsq);
        split_bf16(v[j], hi[j], lo[j]);
    }
    const int rgall = srow >> 4, row15 = srow & 15;
    const int base = rgall * 512 + row15 * 8;
    const int g0 = shalf * 2;
    short8 h0, h1, l0v, l1v;
#pragma unroll
    for (int j = 0; j < 8; ++j) {
        h0[j]  = (short)hi[j];  h1[j]  = (short)hi[j + 8];
        l0v[j] = (short)lo[j];  l1v[j] = (short)lo[j + 8];
    }
    *(short8*)(Ahi + base + (g0    ) * 128) = h0;
    *(short8*)(Ahi + base + (g0 + 1) * 128) = h1;
    *(short8*)(Alo + base + (g0    ) * 128) = l0v;
    *(short8*)(Alo + base + (g0 + 1) * 128) = l1v;
    uint4* qd = (uint4*)Q;
#pragma unroll
    for (int i = 0; i < 4; ++i) qd[t + 256 * i] = r.q[i];
    return nsq;
}

__global__ __launch_bounds__(256, 2) void scan_mfma_kernel(
        const float* __restrict__ corpus,
        const unsigned short* __restrict__ qws,
        float* __restrict__ cand_s,
        int*   __restrict__ cand_i,
        int nblk) {
    __shared__ __align__(16) unsigned char smem[49152];
    unsigned short* Ahi = (unsigned short*)smem;            // 8 KB [rg8][g4][row15][e8]
    unsigned short* Alo = Ahi + 4096;                       // 8 KB
    unsigned short* Q   = Ahi + 8192;                       // 16 KB: hi 4096, lo 4096 ushorts
    float* normp = (float*)(smem + 32768);                  // [128][2]
    float* invn  = (float*)(smem + 33792);                  // [128]

    const int t = threadIdx.x;
    const int w = t >> 6;      // wave 0..3
    const int l = t & 63;      // lane

    float ts[8][3]; int ti[8][3];
#pragma unroll
    for (int qg = 0; qg < 8; ++qg)
#pragma unroll
        for (int j = 0; j < 3; ++j) { ts[qg][j] = -1e30f; ti[qg][j] = 0; }

    const int ntiles = (NCORP + TR - 1) / TR;
    for (int tile = blockIdx.x; tile < ntiles; tile += nblk) {
        const int r0 = tile * TR;
        floatx4 acc[2][8];
#pragma unroll
        for (int rg = 0; rg < 2; ++rg)
#pragma unroll
            for (int qg = 0; qg < 8; ++qg)
#pragma unroll
                for (int j = 0; j < 4; ++j) acc[rg][qg][j] = 0.f;

        float nsq = 0.f;
        {   // prologue: stage chunk 0
            StageRegs r;
            stage_load(r, corpus, qws, r0, 0, t);
            nsq += stage_write(r, Ahi, Alo, Q, t);
        }
        __syncthreads();

        for (int kc = 0; kc < NCH; ++kc) {
            StageRegs r;
            const bool pf = (kc + 1 < NCH);
            if (pf) stage_load(r, corpus, qws, r0, kc + 1, t);   // T14 issue-early

            short8 ahi[2], alo[2];
#pragma unroll
            for (int rg = 0; rg < 2; ++rg) {
                ahi[rg] = *(const short8*)(Ahi + (w * 2 + rg) * 512 + l * 8);
                alo[rg] = *(const short8*)(Alo + (w * 2 + rg) * 512 + l * 8);
            }
#pragma unroll
            for (int qg = 0; qg < 8; ++qg) {
                const short8 bhi = *(const short8*)(Q + qg * 512 + l * 8);
                const short8 blo = *(const short8*)(Q + 4096 + qg * 512 + l * 8);
#pragma unroll
                for (int rg = 0; rg < 2; ++rg) {
                    acc[rg][qg] = __builtin_amdgcn_mfma_f32_16x16x32_bf16(ahi[rg], bhi, acc[rg][qg], 0, 0, 0);
                    acc[rg][qg] = __builtin_amdgcn_mfma_f32_16x16x32_bf16(ahi[rg], blo, acc[rg][qg], 0, 0, 0);
                    acc[rg][qg] = __builtin_amdgcn_mfma_f32_16x16x32_bf16(alo[rg], bhi, acc[rg][qg], 0, 0, 0);
                }
            }
            __syncthreads();                      // done reading LDS chunk kc
            if (pf) nsq += stage_write(r, Ahi, Alo, Q, t);  // write-late
            __syncthreads();                      // chunk kc+1 ready
        }

        // corpus row norms
        normp[(t >> 1) * 2 + (t & 1)] = nsq;
        __syncthreads();
        if (t < B_Q) {
            const float s = normp[t * 2] + normp[t * 2 + 1];
            invn[t] = 1.0f / fmaxf(sqrtf(s), 1e-6f);
        }
        __syncthreads();

        // scores -> per-lane running top3
#pragma unroll
        for (int rg = 0; rg < 2; ++rg) {
#pragma unroll
            for (int reg = 0; reg < 4; ++reg) {
                const int rl = w * 32 + rg * 16 + ((l >> 4) << 2) + reg;
                const int rglob = r0 + rl;
                const float iv = invn[rl];
                if (rglob < NCORP) {
#pragma unroll
                    for (int qg = 0; qg < 8; ++qg) {
                        const float s = acc[rg][qg][reg] * iv;
                        ins3(s, rglob, ts[qg][0], ts[qg][1], ts[qg][2],
                                       ti[qg][0], ti[qg][1], ti[qg][2]);
                    }
                }
            }
        }
        __syncthreads();   // invn reads done before next tile reuses LDS
    }

    // block-level merge: 16 slots x 3 per query -> per-block top-3
    float* msc = (float*)smem;            // [128][16][3]
    int*   mid = (int*)(smem + 24576);
    __syncthreads();
#pragma unroll
    for (int qg = 0; qg < 8; ++qg) {
        const int q = qg * 16 + (l & 15);
        const int slot = w * 4 + (l >> 4);
#pragma unroll
        for (int j = 0; j < 3; ++j) {
            msc[(q * 16 + slot) * 3 + j] = ts[qg][j];
            mid[(q * 16 + slot) * 3 + j] = ti[qg][j];
        }
    }
    __syncthreads();
    if (t < B_Q) {
        float b0 = -1e30f, b1 = -1e30f, b2 = -1e30f;
        int   i0 = 0, i1 = 0, i2 = 0;
        for (int e = 0; e < 48; ++e)
            ins3(msc[t * 48 + e], mid[t * 48 + e], b0, b1, b2, i0, i1, i2);
        const size_t base = ((size_t)blockIdx.x * B_Q + t) * 3;
        cand_s[base + 0] = b0; cand_s[base + 1] = b1; cand_s[base + 2] = b2;
        cand_i[base + 0] = i0; cand_i[base + 1] = i1; cand_i[base + 2] = i2;
    }
}

// ---------------------------------------------------------------------------
// Kernel C: reduce per-block candidates -> global top-3 per query; write out.
// d_out: [0..383] scores f32, [384..767] indices stored as f32 values.
// ---------------------------------------------------------------------------
__global__ void final_topk_kernel(const float* __restrict__ cand_s,
                                  const int*   __restrict__ cand_i,
                                  int nblk,
                                  float* __restrict__ out) {
    __shared__ float ls[256 * 3];
    __shared__ int   li[256 * 3];
    const int q = blockIdx.x;
    const int t = threadIdx.x;

    float b0 = -1e30f, b1 = -1e30f, b2 = -1e30f;
    int   i0 = 0, i1 = 0, i2 = 0;
    for (int blk = t; blk < nblk; blk += 256) {
        const size_t base = ((size_t)blk * B_Q + q) * 3;
#pragma unroll
        for (int j = 0; j < 3; ++j)
            ins3(cand_s[base + j], cand_i[base + j], b0, b1, b2, i0, i1, i2);
    }
    ls[t * 3 + 0] = b0; ls[t * 3 + 1] = b1; ls[t * 3 + 2] = b2;
    li[t * 3 + 0] = i0; li[t * 3 + 1] = i1; li[t * 3 + 2] = i2;
    __syncthreads();

    if (t == 0) {
        float c0 = -1e30f, c1 = -1e30f, c2 = -1e30f;
        int   j0 = 0, j1 = 0, j2 = 0;
        for (int e = 0; e < 256 * 3; ++e)
            ins3(ls[e], li[e], c0, c1, c2, j0, j1, j2);
        out[q * 3 + 0] = c0;
        out[q * 3 + 1] = c1;
        out[q * 3 + 2] = c2;
        out[B_Q * 3 + q * 3 + 0] = (float)j0;
        out[B_Q * 3 + q * 3 + 1] = (float)j1;
        out[B_Q * 3 + q * 3 + 2] = (float)j2;
    }
}

// ---------------------------------------------------------------------------
extern "C" void kernel_launch(void* const* d_in, const int* in_sizes, int n_in,
                              void* d_out, int out_size, void* d_ws, size_t ws_size,
                              hipStream_t stream) {
    const float* qr     = (const float*)d_in[0];  // [128,512]
    const float* corpus = (const float*)d_in[1];  // [500000,512]
    const float* W      = (const float*)d_in[2];  // [512,512]

    float* out = (float*)d_out;
    char*  ws  = (char*)d_ws;

    unsigned short* qws = (unsigned short*)ws;            // 16 chunks * 16 KB = 256 KB
    const size_t qbytes = (size_t)NCH * 16384;

    const int ntiles = (NCORP + TR - 1) / TR;             // 3907
    const size_t per_blk = (size_t)B_Q * 3 * (sizeof(float) + sizeof(int));
    int nblk = ntiles;
    const size_t avail = ws_size > qbytes ? ws_size - qbytes : 0;
    if ((size_t)nblk * per_blk > avail) nblk = (int)(avail / per_blk);
    if (nblk < 1) nblk = 1;

    float* cand_s = (float*)(ws + qbytes);
    int*   cand_i = (int*)(ws + qbytes + (size_t)nblk * B_Q * 3 * sizeof(float));

    proj_split_kernel<<<B_Q, 256, 0, stream>>>(qr, W, qws);
    scan_mfma_kernel<<<nblk, 256, 0, stream>>>(corpus, qws, cand_s, cand_i, nblk);
    final_topk_kernel<<<B_Q, 256, 0, stream>>>(cand_s, cand_i, nblk, out);
}

// Round 3
// 685.986 us; speedup vs baseline: 2.6435x; 1.6700x over previous
//
#include <hip/hip_runtime.h>
#include <math.h>

#define B_Q   128
#define DIM   512
#define NCORP 500000
#define TR    128           // corpus rows per block tile
#define NCH   16            // K chunks of 32 (512/32)

typedef short short8 __attribute__((ext_vector_type(8)));
typedef float floatx4 __attribute__((ext_vector_type(4)));

__device__ __forceinline__ unsigned short bf16_rne(float x) {
    unsigned u = __float_as_uint(x);
    return (unsigned short)((u + 0x7FFFu + ((u >> 16) & 1u)) >> 16);
}

__device__ __forceinline__ void ins3(float s, int id,
                                     float& b0, float& b1, float& b2,
                                     int& i0, int& i1, int& i2) {
    if (s > b0)      { b2 = b1; i2 = i1; b1 = b0; i1 = i0; b0 = s; i0 = id; }
    else if (s > b1) { b2 = b1; i2 = i1; b1 = s;  i1 = id; }
    else if (s > b2) { b2 = s;  i2 = id; }
}

__device__ __forceinline__ void ins2(float s, int id,
                                     float& b0, float& b1, int& i0, int& i1) {
    if (s > b0)      { b1 = b0; i1 = i0; b0 = s; i0 = id; }
    else if (s > b1) { b1 = s;  i1 = id; }
}

__device__ __forceinline__ void ins8(float s, int id, float* bs, int* bi) {
#pragma unroll
    for (int j = 0; j < 8; ++j) {
        if (s > bs[j]) {
            float tf = bs[j]; int tx = bi[j];
            bs[j] = s; bi[j] = id; s = tf; id = tx;
        }
    }
}

// ---------------------------------------------------------------------------
// Kernel A: query = query_r @ W ; L2-normalize ; write
//  (a) exact qn f32 row-major  (for rescore)
//  (b) bf16 MFMA B-fragment-linear layout:
//      qfrag idx = kc*4096 + qg*512 + (g*16 + q15)*8 + e
// ---------------------------------------------------------------------------
__global__ void proj_kernel(const float* __restrict__ qr,
                            const float* __restrict__ W,
                            float* __restrict__ qn,
                            unsigned short* __restrict__ qfrag) {
    __shared__ float qrow[DIM];
    __shared__ float red[256];
    const int b = blockIdx.x;
    const int t = threadIdx.x;

    qrow[t]       = qr[b * DIM + t];
    qrow[t + 256] = qr[b * DIM + t + 256];
    __syncthreads();

    float acc0 = 0.f, acc1 = 0.f;
#pragma unroll 8
    for (int k = 0; k < DIM; ++k) {
        const float q = qrow[k];
        acc0 = fmaf(q, W[k * DIM + t],       acc0);
        acc1 = fmaf(q, W[k * DIM + t + 256], acc1);
    }

    red[t] = acc0 * acc0 + acc1 * acc1;
    __syncthreads();
    for (int s = 128; s > 0; s >>= 1) {
        if (t < s) red[t] += red[t + s];
        __syncthreads();
    }
    const float inv = 1.0f / fmaxf(sqrtf(red[0]), 1e-6f);

    const int qg = b >> 4, q15 = b & 15;
#pragma unroll
    for (int half = 0; half < 2; ++half) {
        const int d = t + half * 256;
        const float x = (half == 0 ? acc0 : acc1) * inv;
        qn[b * DIM + d] = x;
        const int kc = d >> 5, kk = d & 31, g = kk >> 3, e = kk & 7;
        qfrag[(size_t)kc * 4096 + qg * 512 + (g * 16 + q15) * 8 + e] = bf16_rne(x);
    }
}

// ---------------------------------------------------------------------------
// Kernel B: bf16 1-pass MFMA cosine scan (approx) + per-block top-3.
// Double-buffered LDS, 1 barrier per chunk. Per-lane top-2 per query slot.
// ---------------------------------------------------------------------------
__global__ __launch_bounds__(256, 3) void scan_bf16_kernel(
        const float* __restrict__ corpus,
        const unsigned short* __restrict__ qfrag,
        float* __restrict__ cand_s,
        int*   __restrict__ cand_i,
        int nblk) {
    __shared__ __align__(16) unsigned char smem[34304];
    unsigned short* A0 = (unsigned short*)smem;               // [2][4096] ushort
    unsigned short* Q0 = (unsigned short*)(smem + 16384);     // [2][4096] ushort
    float* normp = (float*)(smem + 32768);                    // [128][2]
    float* invn  = (float*)(smem + 33792);                    // [128]

    const int t = threadIdx.x;
    const int w = t >> 6, l = t & 63;
    const int srow = t >> 1, shalf = t & 1;
    const int abase = (srow >> 4) * 512 + (srow & 15) * 8;
    const int g0 = shalf * 2;

    float ts[8][2]; int ti[8][2];
#pragma unroll
    for (int qg = 0; qg < 8; ++qg) {
        ts[qg][0] = -1e30f; ts[qg][1] = -1e30f;
        ti[qg][0] = -1;     ti[qg][1] = -1;
    }

    const int ntiles = (NCORP + TR - 1) / TR;
    for (int tile = blockIdx.x; tile < ntiles; tile += nblk) {
        const int r0 = tile * TR;
        floatx4 acc[2][8];
#pragma unroll
        for (int rg = 0; rg < 2; ++rg)
#pragma unroll
            for (int qg = 0; qg < 8; ++qg)
#pragma unroll
                for (int j = 0; j < 4; ++j) acc[rg][qg][j] = 0.f;

        float nsq = 0.f;
        int rr = r0 + srow; if (rr > NCORP - 1) rr = NCORP - 1;
        const float* crow = corpus + (size_t)rr * DIM + shalf * 16;

        // ---- prologue: stage chunk 0 into buf 0 ----
        {
            const float* src = crow;
            float4 c0 = *(const float4*)(src);
            float4 c1 = *(const float4*)(src + 4);
            float4 c2 = *(const float4*)(src + 8);
            float4 c3 = *(const float4*)(src + 12);
            const uint4* qs = (const uint4*)(qfrag);
            uint4 qa = qs[t], qb = qs[t + 256];
            float v[16];
            v[0]=c0.x; v[1]=c0.y; v[2]=c0.z; v[3]=c0.w;
            v[4]=c1.x; v[5]=c1.y; v[6]=c1.z; v[7]=c1.w;
            v[8]=c2.x; v[9]=c2.y; v[10]=c2.z; v[11]=c2.w;
            v[12]=c3.x; v[13]=c3.y; v[14]=c3.z; v[15]=c3.w;
            short8 h0, h1;
#pragma unroll
            for (int j = 0; j < 8; ++j) {
                nsq = fmaf(v[j], v[j], nsq);
                nsq = fmaf(v[j+8], v[j+8], nsq);
                h0[j] = (short)bf16_rne(v[j]);
                h1[j] = (short)bf16_rne(v[j+8]);
            }
            *(short8*)(A0 + abase + (g0    ) * 128) = h0;
            *(short8*)(A0 + abase + (g0 + 1) * 128) = h1;
            ((uint4*)Q0)[t] = qa;
            ((uint4*)Q0)[t + 256] = qb;
        }
        __syncthreads();

        for (int kc = 0; kc < NCH; ++kc) {
            const int d = kc & 1;
            unsigned short* Ad = A0 + d * 4096;
            unsigned short* Qd = Q0 + d * 4096;
            unsigned short* An = A0 + (d ^ 1) * 4096;
            unsigned short* Qn = Q0 + (d ^ 1) * 4096;
            const bool pf = (kc + 1 < NCH);

            float v[16]; uint4 qa, qb;
            if (pf) {                               // issue next-chunk loads early
                const float* src = crow + (kc + 1) * 32;
                float4 c0 = *(const float4*)(src);
                float4 c1 = *(const float4*)(src + 4);
                float4 c2 = *(const float4*)(src + 8);
                float4 c3 = *(const float4*)(src + 12);
                const uint4* qs = (const uint4*)(qfrag + (size_t)(kc + 1) * 4096);
                qa = qs[t]; qb = qs[t + 256];
                v[0]=c0.x; v[1]=c0.y; v[2]=c0.z; v[3]=c0.w;
                v[4]=c1.x; v[5]=c1.y; v[6]=c1.z; v[7]=c1.w;
                v[8]=c2.x; v[9]=c2.y; v[10]=c2.z; v[11]=c2.w;
                v[12]=c3.x; v[13]=c3.y; v[14]=c3.z; v[15]=c3.w;
            }

            // MFMA on buf d
            short8 a0 = *(const short8*)(Ad + (w * 2 + 0) * 512 + l * 8);
            short8 a1 = *(const short8*)(Ad + (w * 2 + 1) * 512 + l * 8);
#pragma unroll
            for (int qg = 0; qg < 8; ++qg) {
                short8 bq = *(const short8*)(Qd + qg * 512 + l * 8);
                acc[0][qg] = __builtin_amdgcn_mfma_f32_16x16x32_bf16(a0, bq, acc[0][qg], 0, 0, 0);
                acc[1][qg] = __builtin_amdgcn_mfma_f32_16x16x32_bf16(a1, bq, acc[1][qg], 0, 0, 0);
            }

            if (pf) {                               // convert + write next buf
                short8 h0, h1;
#pragma unroll
                for (int j = 0; j < 8; ++j) {
                    nsq = fmaf(v[j], v[j], nsq);
                    nsq = fmaf(v[j+8], v[j+8], nsq);
                    h0[j] = (short)bf16_rne(v[j]);
                    h1[j] = (short)bf16_rne(v[j+8]);
                }
                *(short8*)(An + abase + (g0    ) * 128) = h0;
                *(short8*)(An + abase + (g0 + 1) * 128) = h1;
                ((uint4*)Qn)[t] = qa;
                ((uint4*)Qn)[t + 256] = qb;
            }
            __syncthreads();
        }

        // corpus row norms
        normp[srow * 2 + shalf] = nsq;
        __syncthreads();
        if (t < B_Q) {
            const float s2 = normp[t * 2] + normp[t * 2 + 1];
            invn[t] = 1.0f / fmaxf(sqrtf(s2), 1e-6f);
        }
        __syncthreads();

        // scores -> per-lane running top2 per query slot
#pragma unroll
        for (int rg = 0; rg < 2; ++rg) {
#pragma unroll
            for (int reg = 0; reg < 4; ++reg) {
                const int rl = w * 32 + rg * 16 + ((l >> 4) << 2) + reg;
                const int rglob = r0 + rl;
                const float iv = invn[rl];
                if (rglob < NCORP) {
#pragma unroll
                    for (int qg = 0; qg < 8; ++qg) {
                        const float s = acc[rg][qg][reg] * iv;
                        ins2(s, rglob, ts[qg][0], ts[qg][1], ti[qg][0], ti[qg][1]);
                    }
                }
            }
        }
        __syncthreads();
    }

    // block merge: 16 slots x 2 per query -> per-block top-3
    float* msc = (float*)smem;                 // [128][16][2] = 16 KB
    int*   mid = (int*)(smem + 16384);         // [128][16][2] = 16 KB
#pragma unroll
    for (int qg = 0; qg < 8; ++qg) {
        const int q = qg * 16 + (l & 15);
        const int slot = w * 4 + (l >> 4);
#pragma unroll
        for (int j = 0; j < 2; ++j) {
            msc[(q * 16 + slot) * 2 + j] = ts[qg][j];
            mid[(q * 16 + slot) * 2 + j] = ti[qg][j];
        }
    }
    __syncthreads();
    if (t < B_Q) {
        float b0 = -1e30f, b1 = -1e30f, b2 = -1e30f;
        int   i0 = -1, i1 = -1, i2 = -1;
        for (int e = 0; e < 32; ++e)
            ins3(msc[t * 32 + e], mid[t * 32 + e], b0, b1, b2, i0, i1, i2);
        const size_t base = ((size_t)blockIdx.x * B_Q + t) * 3;
        cand_s[base + 0] = b0; cand_s[base + 1] = b1; cand_s[base + 2] = b2;
        cand_i[base + 0] = i0; cand_i[base + 1] = i1; cand_i[base + 2] = i2;
    }
}

// ---------------------------------------------------------------------------
// Kernel C: merge per-block candidates -> global approx top-8 per query.
// ---------------------------------------------------------------------------
__global__ void merge_topk_kernel(const float* __restrict__ cand_s,
                                  const int*   __restrict__ cand_i,
                                  int nblk,
                                  float* __restrict__ topT_s,
                                  int*   __restrict__ topT_i) {
    __shared__ float ls[256 * 8];
    __shared__ int   li[256 * 8];
    const int q = blockIdx.x;
    const int t = threadIdx.x;

    float bs[8]; int bi[8];
#pragma unroll
    for (int j = 0; j < 8; ++j) { bs[j] = -1e30f; bi[j] = -1; }

    for (int blk = t; blk < nblk; blk += 256) {
        const size_t base = ((size_t)blk * B_Q + q) * 3;
#pragma unroll
        for (int j = 0; j < 3; ++j)
            ins8(cand_s[base + j], cand_i[base + j], bs, bi);
    }
#pragma unroll
    for (int j = 0; j < 8; ++j) { ls[t * 8 + j] = bs[j]; li[t * 8 + j] = bi[j]; }
    __syncthreads();

    for (int s = 128; s > 0; s >>= 1) {
        if (t < s) {
#pragma unroll
            for (int j = 0; j < 8; ++j)
                ins8(ls[(t + s) * 8 + j], li[(t + s) * 8 + j], bs, bi);
#pragma unroll
            for (int j = 0; j < 8; ++j) { ls[t * 8 + j] = bs[j]; li[t * 8 + j] = bi[j]; }
        }
        __syncthreads();
    }
    if (t == 0) {
#pragma unroll
        for (int j = 0; j < 8; ++j) { topT_s[q * 8 + j] = bs[j]; topT_i[q * 8 + j] = bi[j]; }
    }
}

// ---------------------------------------------------------------------------
// Kernel D: exact f32 rescore of 8 candidates per query -> top-3 -> out.
// d_out: [0..383] scores f32, [384..767] indices stored as f32 values.
// ---------------------------------------------------------------------------
__global__ void rescore_kernel(const float* __restrict__ corpus,
                               const float* __restrict__ qn,
                               const int*   __restrict__ topT_i,
                               float* __restrict__ out) {
    __shared__ float qrow[DIM];
    __shared__ float sc[8];
    const int q = blockIdx.x;
    const int t = threadIdx.x;
    const int g = t >> 5;       // candidate 0..7
    const int lane = t & 31;

    qrow[t]       = qn[q * DIM + t];
    qrow[t + 256] = qn[q * DIM + t + 256];
    __syncthreads();

    const int r = topT_i[q * 8 + g];
    float d = 0.f, n = 0.f;
    if (r >= 0) {
        const float* row = corpus + (size_t)r * DIM;
        for (int j = lane; j < DIM; j += 32) {
            const float c = row[j];
            d = fmaf(qrow[j], c, d);
            n = fmaf(c, c, n);
        }
    }
#pragma unroll
    for (int m = 16; m > 0; m >>= 1) {
        d += __shfl_xor(d, m);
        n += __shfl_xor(n, m);
    }
    if (lane == 0)
        sc[g] = (r >= 0) ? d / fmaxf(sqrtf(n), 1e-6f) : -1e30f;
    __syncthreads();

    if (t == 0) {
        float b0 = -1e30f, b1 = -1e30f, b2 = -1e30f;
        int   i0 = 0, i1 = 0, i2 = 0;
#pragma unroll
        for (int e = 0; e < 8; ++e)
            ins3(sc[e], topT_i[q * 8 + e], b0, b1, b2, i0, i1, i2);
        out[q * 3 + 0] = b0;
        out[q * 3 + 1] = b1;
        out[q * 3 + 2] = b2;
        out[B_Q * 3 + q * 3 + 0] = (float)i0;
        out[B_Q * 3 + q * 3 + 1] = (float)i1;
        out[B_Q * 3 + q * 3 + 2] = (float)i2;
    }
}

// ---------------------------------------------------------------------------
extern "C" void kernel_launch(void* const* d_in, const int* in_sizes, int n_in,
                              void* d_out, int out_size, void* d_ws, size_t ws_size,
                              hipStream_t stream) {
    const float* qr     = (const float*)d_in[0];  // [128,512]
    const float* corpus = (const float*)d_in[1];  // [500000,512]
    const float* W      = (const float*)d_in[2];  // [512,512]

    float* out = (float*)d_out;
    char*  ws  = (char*)d_ws;

    float*          qn    = (float*)ws;                       // 256 KB
    unsigned short* qfrag = (unsigned short*)(ws + 262144);   // 128 KB
    float*          topT_s = (float*)(ws + 393216);           // 4 KB
    int*            topT_i = (int*)(ws + 397312);             // 4 KB
    const size_t head = 401408;

    const int ntiles = (NCORP + TR - 1) / TR;                 // 3907
    const size_t per_blk = (size_t)B_Q * 3 * (sizeof(float) + sizeof(int));
    int nblk = ntiles;
    const size_t avail = ws_size > head ? ws_size - head : 0;
    if ((size_t)nblk * per_blk > avail) nblk = (int)(avail / per_blk);
    if (nblk < 1) nblk = 1;

    float* cand_s = (float*)(ws + head);
    int*   cand_i = (int*)(ws + head + (size_t)nblk * B_Q * 3 * sizeof(float));

    proj_kernel<<<B_Q, 256, 0, stream>>>(qr, W, qn, qfrag);
    scan_bf16_kernel<<<nblk, 256, 0, stream>>>(corpus, qfrag, cand_s, cand_i, nblk);
    merge_topk_kernel<<<B_Q, 256, 0, stream>>>(cand_s, cand_i, nblk, topT_s, topT_i);
    rescore_kernel<<<B_Q, 256, 0, stream>>>(corpus, qn, topT_i, out);
}